// Round 5
// baseline (190.483 us; speedup 1.0000x reference)
//
#include <hip/hip_runtime.h>
#include <hip/hip_cooperative_groups.h>

namespace cg = cooperative_groups;

// Performer causal linear attention (generalized relu kernel), fp32.
// B=1, H=8, N=1024, D=64, M=128. Chunked formulation, chunk C=128:
//   qp = relu(norm * q @ proj^T) + eps ; kp likewise
//   Z  = cumsum_n kp ; W = qp / Z
//   out_c = W_c @ S0_c + tril(W_c @ Kp_c^T) @ V_c ; S0_c = prefix of Kp^T V
// R5: single cooperative mega-kernel (256 blocks x 512 thr), phases split by
// grid.sync(): P1 proj q/k + 32-row G partials + kpart; P2 chunk-prefix scan
// (S0 into Gp seg-0 slots) + W=qp/Z; P3 fused A-in-LDS attention.
static constexpr int H = 8, N = 1024, D = 64, M = 128, CHUNK = 128, NC = 8;
static constexpr float EPS = 1e-3f;
static constexpr float NORM = 0.35355339059327373f; // 64^-0.25

__global__ __launch_bounds__(512) void k_all(const float* __restrict__ q,
                                             const float* __restrict__ k,
                                             const float* __restrict__ v,
                                             const float* __restrict__ proj,
                                             float* __restrict__ qp,
                                             float* __restrict__ kp,
                                             float* __restrict__ kpart,
                                             float* __restrict__ Gp,
                                             float* __restrict__ out) {
    __shared__ __align__(16) float smem[15104]; // 60.4 KB union for all phases
    const int tid = threadIdx.x;
    const int b = blockIdx.x;
    cg::grid_group grid = cg::this_grid();

    // ================= P1: proj (q & k) + G partial + kpart =================
    {
        float* plT = smem;        // [d][m] stride 132 (8448 floats)
        float* xlT = smem + 8448; // [d][r] stride 36  (2304 floats)
        const int h = b >> 5, rblk = b & 31;
        const int rowbase = h * N + rblk * 32;

        for (int i = tid; i < M * D; i += 512) {
            int m = i >> 6, d = i & 63;
            plT[d * 132 + m] = proj[i];
        }
        for (int i = tid; i < 32 * D; i += 512) {
            int r = i >> 6, d = i & 63;
            xlT[d * 36 + r] = q[(rowbase + r) * D + d] * NORM;
        }
        __syncthreads();

        const int m0 = (tid & 31) * 4; // 32 groups x 4 m
        const int r0 = (tid >> 5) * 2; // 16 groups x 2 r
        // ---- q-side GEMM
        {
            float acc[2][4] = {};
#pragma unroll 8
            for (int d = 0; d < 64; d++) {
                float2 xv = *(const float2*)&xlT[d * 36 + r0];
                float4 pv = *(const float4*)&plT[d * 132 + m0];
                const float xr[2] = {xv.x, xv.y};
                const float pr[4] = {pv.x, pv.y, pv.z, pv.w};
#pragma unroll
                for (int ri = 0; ri < 2; ri++)
#pragma unroll
                    for (int mi = 0; mi < 4; mi++) acc[ri][mi] += xr[ri] * pr[mi];
            }
#pragma unroll
            for (int ri = 0; ri < 2; ri++) {
                float4 s;
                s.x = fmaxf(acc[ri][0], 0.f) + EPS;
                s.y = fmaxf(acc[ri][1], 0.f) + EPS;
                s.z = fmaxf(acc[ri][2], 0.f) + EPS;
                s.w = fmaxf(acc[ri][3], 0.f) + EPS;
                *(float4*)&qp[(rowbase + r0 + ri) * M + m0] = s;
            }
        }
        __syncthreads(); // xlT free
        for (int i = tid; i < 32 * D; i += 512) {
            int r = i >> 6, d = i & 63;
            xlT[d * 36 + r] = k[(rowbase + r) * D + d] * NORM;
        }
        __syncthreads();
        // ---- k-side GEMM (keep results in regs for G)
        float4 sv[2];
        {
            float acc[2][4] = {};
#pragma unroll 8
            for (int d = 0; d < 64; d++) {
                float2 xv = *(const float2*)&xlT[d * 36 + r0];
                float4 pv = *(const float4*)&plT[d * 132 + m0];
                const float xr[2] = {xv.x, xv.y};
                const float pr[4] = {pv.x, pv.y, pv.z, pv.w};
#pragma unroll
                for (int ri = 0; ri < 2; ri++)
#pragma unroll
                    for (int mi = 0; mi < 4; mi++) acc[ri][mi] += xr[ri] * pr[mi];
            }
#pragma unroll
            for (int ri = 0; ri < 2; ri++) {
                sv[ri].x = fmaxf(acc[ri][0], 0.f) + EPS;
                sv[ri].y = fmaxf(acc[ri][1], 0.f) + EPS;
                sv[ri].z = fmaxf(acc[ri][2], 0.f) + EPS;
                sv[ri].w = fmaxf(acc[ri][3], 0.f) + EPS;
                *(float4*)&kp[(rowbase + r0 + ri) * M + m0] = sv[ri];
            }
        }
        __syncthreads(); // plT/xlT free
        // ---- G partial: kp_tile^T (128m) x v_tile (64e)
        float* kpl = smem;       // [r][m] stride 132 (4224 floats)
        float* vl = smem + 8448; // [r][e] stride 68  (2176 floats)
#pragma unroll
        for (int ri = 0; ri < 2; ri++)
            *(float4*)&kpl[(r0 + ri) * 132 + m0] = sv[ri];
        for (int i = tid; i < 32 * D; i += 512) {
            int r = i >> 6, e = i & 63;
            vl[r * 68 + e] = v[(rowbase + r) * D + e];
        }
        __syncthreads();

        const int gb = h * 32 + rblk;
        const int mg = (tid >> 4) * 4, eg = (tid & 15) * 4;
        float ag[4][4] = {};
#pragma unroll 4
        for (int nn = 0; nn < 32; nn++) {
            float4 kv = *(const float4*)&kpl[nn * 132 + mg];
            float4 vv = *(const float4*)&vl[nn * 68 + eg];
            const float kr[4] = {kv.x, kv.y, kv.z, kv.w};
            const float vr[4] = {vv.x, vv.y, vv.z, vv.w};
#pragma unroll
            for (int mi = 0; mi < 4; mi++)
#pragma unroll
                for (int ej = 0; ej < 4; ej++) ag[mi][ej] += kr[mi] * vr[ej];
        }
#pragma unroll
        for (int mi = 0; mi < 4; mi++) {
            float4 a = {ag[mi][0], ag[mi][1], ag[mi][2], ag[mi][3]};
            *(float4*)&Gp[(gb * M + mg + mi) * D + eg] = a;
        }
        if (tid < 128) {
            float ks = 0.f;
#pragma unroll 8
            for (int nn = 0; nn < 32; nn++) ks += kpl[nn * 132 + tid];
            kpart[gb * M + tid] = ks;
        }
    }

    grid.sync();

    // ====== P2: (blocks 0-127) S0 chunk-prefix into Gp seg-0 slots;
    //        (blocks 128-191) W = qp / Z with 32-row serial segments ======
    if (b < 128) {
        const int g = b * 512 + tid; // 65536 = H * M*D
        const int h = g >> 13, i = g & 8191;
        float run = 0.f;
#pragma unroll
        for (int c = 0; c < NC; c++) {
            const int g0 = (h * 32 + c * 4) * (M * D) + i;
            float s = Gp[g0] + Gp[g0 + M * D] + Gp[g0 + 2 * M * D] +
                      Gp[g0 + 3 * M * D];
            Gp[g0] = run;
            run += s;
        }
    } else if (b < 192) {
        const int g = (b - 128) * 512 + tid; // 32768 = 256 segs x 128 m
        const int seg = g >> 7, m = g & 127;
        const int h = seg >> 5, s = seg & 31;
        float z = 0.f;
        for (int sp = 0; sp < s; sp++) z += kpart[(h * 32 + sp) * M + m];
        int idx = (h * N + s * 32) * M + m;
#pragma unroll 4
        for (int n = 0; n < 32; n++, idx += M) {
            z += kp[idx];
            qp[idx] = qp[idx] * __builtin_amdgcn_rcpf(z);
        }
    }

    grid.sync();

    // ========= P3: A = tril(W @ Kp^T) in LDS; out = W@S0 + A@V =========
    {
        float* AT = smem;         // [j][n] 128x68 (8704)
        float* Ut = smem + 8704;  // [kk][n] 32x68 (2176)
        float* Kt = smem + 10880; // [mm][j] 32x132 (4224); aliased Xs
        float* Xs = Kt;
        const float* __restrict__ W = qp;
        const int hc = b >> 2;
        const int h = hc >> 3, c = hc & 7;
        const int half = (b >> 1) & 1;
        const int eh = b & 1;
        const int rowbase = h * N + c * CHUNK + half * 64;

        // phase 1: A = tril(W_half @ kp_c^T) -> AT[j][n]
        {
            const int n0 = (tid >> 5) * 4; // 16 groups x 4 = 64 n
            const int j0 = (tid & 31) * 4; // 32 groups x 4 = 128 j
            float acc[4][4] = {};
            for (int mc = 0; mc < 4; mc++) {
                const int m0 = mc * 32;
                for (int i = tid; i < 2048; i += 512) {
                    int mm = i & 31, n = i >> 5;
                    Ut[mm * 68 + n] = W[(rowbase + n) * M + m0 + mm];
                }
                for (int i = tid; i < 4096; i += 512) {
                    int mm = i & 31, j = i >> 5;
                    Kt[mm * 132 + j] = kp[(h * N + c * CHUNK + j) * M + m0 + mm];
                }
                __syncthreads();
#pragma unroll 8
                for (int mm = 0; mm < 32; mm++) {
                    float4 wa = *(const float4*)&Ut[mm * 68 + n0];
                    float4 ka = *(const float4*)&Kt[mm * 132 + j0];
                    const float wr[4] = {wa.x, wa.y, wa.z, wa.w};
                    const float jr[4] = {ka.x, ka.y, ka.z, ka.w};
#pragma unroll
                    for (int ni = 0; ni < 4; ni++)
#pragma unroll
                        for (int ji = 0; ji < 4; ji++) acc[ni][ji] += wr[ni] * jr[ji];
                }
                __syncthreads();
            }
#pragma unroll
            for (int jj = 0; jj < 4; jj++) {
                const int j = j0 + jj;
                float4 s;
                s.x = (j <= half * 64 + n0 + 0) ? acc[0][jj] : 0.f;
                s.y = (j <= half * 64 + n0 + 1) ? acc[1][jj] : 0.f;
                s.z = (j <= half * 64 + n0 + 2) ? acc[2][jj] : 0.f;
                s.w = (j <= half * 64 + n0 + 3) ? acc[3][jj] : 0.f;
                *(float4*)&AT[j * 68 + n0] = s;
            }
        }

        // phase 2: out[:, eh*32 .. +32] = W @ S0 + A @ V
        {
            const int n2 = tid >> 3;                // 64 n
            const int e0 = eh * 32 + (tid & 7) * 4; // 8 groups x 4 e
            const int s0base = (h * 32 + c * 4) * (M * D);
            float acc2[4] = {};
            for (int kc = 0; kc < 8; kc++) {
                __syncthreads();
                if (kc < 4) {
                    const int k0 = kc * 32;
                    for (int i = tid; i < 2048; i += 512) {
                        int kk = i & 31, n = i >> 5;
                        Ut[kk * 68 + n] = W[(rowbase + n) * M + k0 + kk];
                    }
                    for (int i = tid; i < 2048; i += 512) {
                        int kk = i >> 6, e = i & 63;
                        Xs[kk * 68 + e] = Gp[s0base + (k0 + kk) * D + e];
                    }
                } else {
                    const int k0 = (kc - 4) * 32;
                    for (int i = tid; i < 2048; i += 512) {
                        int kk = i >> 6, e = i & 63;
                        Xs[kk * 68 + e] = v[(h * N + c * CHUNK + k0 + kk) * D + e];
                    }
                }
                __syncthreads();
                const float* ubase = (kc < 4) ? Ut : &AT[(kc - 4) * 32 * 68];
#pragma unroll 8
                for (int kk = 0; kk < 32; kk++) {
                    float uu = ubase[kk * 68 + n2];
                    float4 xx = *(const float4*)&Xs[kk * 68 + e0];
                    acc2[0] += uu * xx.x;
                    acc2[1] += uu * xx.y;
                    acc2[2] += uu * xx.z;
                    acc2[3] += uu * xx.w;
                }
            }
            float4 s = {acc2[0], acc2[1], acc2[2], acc2[3]};
            *(float4*)&out[(rowbase + n2) * D + e0] = s;
        }
    }
}

extern "C" void kernel_launch(void* const* d_in, const int* in_sizes, int n_in,
                              void* d_out, int out_size, void* d_ws, size_t ws_size,
                              hipStream_t stream) {
    const float* q = (const float*)d_in[0];
    const float* k = (const float*)d_in[1];
    const float* v = (const float*)d_in[2];
    const float* proj = (const float*)d_in[3];
    float* out = (float*)d_out;

    // workspace (floats): qp 1M + kp 1M + kpart 32K + Gp 2M = 16.5 MB
    float* ws = (float*)d_ws;
    float* qp = ws;                 // H*N*M (becomes W after P2)
    float* kp = qp + H * N * M;     // H*N*M
    float* kpart = kp + H * N * M;  // H*32*M
    float* Gp = kpart + H * 32 * M; // H*32*M*D (seg-0 slots become S0)

    void* args[] = {(void*)&q,  (void*)&k,     (void*)&v,  (void*)&proj,
                    (void*)&qp, (void*)&kp,    (void*)&kpart,
                    (void*)&Gp, (void*)&out};
    hipLaunchCooperativeKernel((const void*)k_all, dim3(256), dim3(512), args,
                               0, stream);
}

// Round 6
// 105.346 us; speedup vs baseline: 1.8082x; 1.8082x over previous
//
#include <hip/hip_runtime.h>

// Performer causal linear attention (generalized relu kernel), fp32 in/out.
// B=1, H=8, N=1024, D=64, M=128. Chunked formulation, chunk C=128:
//   qp = relu(norm * q @ proj^T) + eps ; kp likewise
//   Z  = cumsum_n kp ; W = qp / Z
//   out_c = W_c @ S0_c + tril(W_c @ Kp_c^T) @ V_c ; S0_c = prefix of Kp^T V
// R6: back to plain multi-kernel (coop launch cost ~75us — reverted).
// k_attn rewritten with bf16 MFMA (16x16x32, fp32 accum): A=W@Kp^T via MFMA,
// masked P round-trips through LDS (C/D->A-operand relayout), out = W@S0 +
// P@V via MFMA with S0^T/V^T staged transposed in LDS. 52KB LDS -> 3 blk/CU.
static constexpr int H = 8, N = 1024, D = 64, M = 128, CHUNK = 128, NC = 8;
static constexpr float EPS = 1e-3f;
static constexpr float NORM = 0.35355339059327373f; // 64^-0.25

typedef __attribute__((ext_vector_type(8))) short short8;
typedef __attribute__((ext_vector_type(4))) float f32x4;

__device__ inline unsigned short f2bf(float x) {
    unsigned u = __float_as_uint(x);
    return (unsigned short)((u + 0x7fffu + ((u >> 16) & 1u)) >> 16);
}

// -------------------------------- K1: qp/kp (+ G partial, kpart, bf16 kp)
// grid (32, H, 2), 256 thr. Block: 32 rows -> 32x128 qp or kp outputs;
// k-side also emits kpb (bf16), Gp[h*32+rblk][M][D], kpart[h*32+rblk][M].
__global__ __launch_bounds__(256) void k_projg(const float* __restrict__ q,
                                               const float* __restrict__ k,
                                               const float* __restrict__ proj,
                                               const float* __restrict__ v,
                                               float* __restrict__ qp,
                                               float* __restrict__ kp,
                                               unsigned short* __restrict__ kpb,
                                               float* __restrict__ Gp,
                                               float* __restrict__ kpart) {
    __shared__ float plT[64 * 132]; // [d][m]; k-side reuses as kpl[32][132]
    __shared__ float xlT[64 * 36];  // [d][r]; k-side reuses as vl[32][68]
    const int tid = threadIdx.x;
    const int rblk = blockIdx.x;
    const int h = blockIdx.y;
    const int which = blockIdx.z;
    const float* __restrict__ x = which ? k : q;
    float* __restrict__ o = which ? kp : qp;

    for (int i = tid; i < M * D; i += 256) {
        int m = i >> 6, d = i & 63;
        plT[d * 132 + m] = proj[i];
    }
    const int rowbase = h * N + rblk * 32;
    for (int i = tid; i < 32 * D; i += 256) {
        int r = i >> 6, d = i & 63;
        xlT[d * 36 + r] = x[(rowbase + r) * D + d] * NORM;
    }
    __syncthreads();

    const int m0 = (tid & 31) * 4;
    const int r0 = (tid >> 5) * 4;
    float acc[4][4] = {};
#pragma unroll 8
    for (int d = 0; d < 64; d++) {
        float4 xv = *(const float4*)&xlT[d * 36 + r0];
        float4 pv = *(const float4*)&plT[d * 132 + m0];
        const float xr[4] = {xv.x, xv.y, xv.z, xv.w};
        const float pr[4] = {pv.x, pv.y, pv.z, pv.w};
#pragma unroll
        for (int ri = 0; ri < 4; ri++)
#pragma unroll
            for (int mi = 0; mi < 4; mi++) acc[ri][mi] += xr[ri] * pr[mi];
    }
    float4 sv[4];
#pragma unroll
    for (int ri = 0; ri < 4; ri++) {
        sv[ri].x = fmaxf(acc[ri][0], 0.f) + EPS;
        sv[ri].y = fmaxf(acc[ri][1], 0.f) + EPS;
        sv[ri].z = fmaxf(acc[ri][2], 0.f) + EPS;
        sv[ri].w = fmaxf(acc[ri][3], 0.f) + EPS;
        *(float4*)&o[(rowbase + r0 + ri) * M + m0] = sv[ri];
    }

    if (!which) return;

    // bf16 copy of kp (packed 2x per uint)
    {
        unsigned int* kpbu = (unsigned int*)kpb;
#pragma unroll
        for (int ri = 0; ri < 4; ri++) {
            unsigned int p0 = (unsigned)f2bf(sv[ri].x) | ((unsigned)f2bf(sv[ri].y) << 16);
            unsigned int p1 = (unsigned)f2bf(sv[ri].z) | ((unsigned)f2bf(sv[ri].w) << 16);
            const int base = (rowbase + r0 + ri) * 64 + (m0 >> 1);
            kpbu[base] = p0;
            kpbu[base + 1] = p1;
        }
    }

    // ---- fused per-32-row G partial: G = kp_tile^T (128m) x v_tile (64e)
    __syncthreads();
    float* kpl = plT; // [r][m] stride 132
    float* vl = xlT;  // [r][e] stride 68
#pragma unroll
    for (int ri = 0; ri < 4; ri++)
        *(float4*)&kpl[(r0 + ri) * 132 + m0] = sv[ri];
    for (int i = tid; i < 32 * D; i += 256) {
        int r = i >> 6, e = i & 63;
        vl[r * 68 + e] = v[(rowbase + r) * D + e];
    }
    __syncthreads();

    const int gb = h * 32 + rblk;
    const int mg = (tid >> 3) * 4, eg = (tid & 7) * 8;
    float ag[4][8] = {};
#pragma unroll 4
    for (int nn = 0; nn < 32; nn++) {
        float4 kv = *(const float4*)&kpl[nn * 132 + mg];
        float4 va = *(const float4*)&vl[nn * 68 + eg];
        float4 vb = *(const float4*)&vl[nn * 68 + eg + 4];
        const float kr[4] = {kv.x, kv.y, kv.z, kv.w};
        const float vr[8] = {va.x, va.y, va.z, va.w, vb.x, vb.y, vb.z, vb.w};
#pragma unroll
        for (int mi = 0; mi < 4; mi++)
#pragma unroll
            for (int ej = 0; ej < 8; ej++) ag[mi][ej] += kr[mi] * vr[ej];
    }
#pragma unroll
    for (int mi = 0; mi < 4; mi++) {
        float4 a = {ag[mi][0], ag[mi][1], ag[mi][2], ag[mi][3]};
        float4 bq = {ag[mi][4], ag[mi][5], ag[mi][6], ag[mi][7]};
        *(float4*)&Gp[(gb * M + mg + mi) * D + eg] = a;
        *(float4*)&Gp[(gb * M + mg + mi) * D + eg + 4] = bq;
    }
    if (tid < 128) {
        float ks = 0.f;
#pragma unroll 8
        for (int nn = 0; nn < 32; nn++) ks += kpl[nn * 132 + tid];
        kpart[gb * M + tid] = ks;
    }
}

// ------------- K2 (merged): blocks 0..255 = S0 chunk-prefix (into Gp seg-0,
// fp32); blocks 256..383 = W = qp/Z emitted as bf16 (WbG).
__global__ __launch_bounds__(256) void k_fix(float* __restrict__ qp,
                                             const float* __restrict__ kp,
                                             const float* __restrict__ kpart,
                                             float* __restrict__ Gp,
                                             unsigned short* __restrict__ WbG) {
    const int b = blockIdx.x;
    if (b < 256) {
        const int g = b * 256 + threadIdx.x; // 65536 = H * M*D
        const int h = g >> 13, i = g & 8191;
        float run = 0.f;
#pragma unroll
        for (int c = 0; c < NC; c++) {
            const int g0 = (h * 32 + c * 4) * (M * D) + i;
            float s = Gp[g0] + Gp[g0 + M * D] + Gp[g0 + 2 * M * D] +
                      Gp[g0 + 3 * M * D];
            Gp[g0] = run;
            run += s;
        }
    } else {
        const int g = (b - 256) * 256 + threadIdx.x; // 32768 = 256 segs x 128
        const int seg = g >> 7, m = g & 127;
        const int h = seg >> 5, s = seg & 31;
        float z = 0.f;
        for (int sp = 0; sp < s; sp++) z += kpart[(h * 32 + sp) * M + m];
        int idx = (h * N + s * 32) * M + m;
#pragma unroll 4
        for (int n = 0; n < 32; n++, idx += M) {
            z += kp[idx];
            WbG[idx] = f2bf(qp[idx] * __builtin_amdgcn_rcpf(z));
        }
    }
}

// ----------------- K3: all-MFMA attention. grid (64, 2 halves), 256 thr.
// P1: A = tril(W @ Kp^T) via mfma_f32_16x16x32_bf16, masked -> Pb (LDS bf16).
// P2: out = W @ S0 + P @ V via MFMA; S0^T / V^T staged transposed in LDS.
__global__ __launch_bounds__(256) void k_attn(const unsigned short* __restrict__ WbG,
                                              const unsigned short* __restrict__ kpb,
                                              const float* __restrict__ Gp,
                                              const float* __restrict__ v,
                                              float* __restrict__ out) {
    __shared__ __align__(16) short smem[26624]; // 52 KB
    short* bufA = smem;          // Wb [64][136] bf16
    short* bufB = smem + 8704;   // Kp m-half [128][72] / S0T,VT [64][136]
    short* bufC = smem + 17920;  // Pb [64][136] bf16
    const int tid = threadIdx.x;
    const int b = blockIdx.x; // h*8 + c
    const int half = blockIdx.y;
    const int h = b >> 3, c = b & 7;
    const int rowbase = h * N + c * CHUNK + half * 64;
    const int chunkbase = h * N + c * CHUNK;
    const int lane = tid & 63, wv = tid >> 6;
    const int fr = lane & 15, fq = lane >> 4;

    // stage Wb: 64 rows x 128 cols bf16 (rows = this half's W rows)
    {
        const unsigned int* src = (const unsigned int*)WbG;
        for (int i = tid; i < 64 * 64; i += 256) {
            int r = i >> 6, cu = i & 63;
            ((unsigned int*)&bufA[r * 136])[cu] = src[(rowbase + r) * 64 + cu];
        }
    }

    const int jtmax = half ? 8 : 4; // half 0: cols j>=64 fully masked
    f32x4 acc1[8];
#pragma unroll
    for (int jt = 0; jt < 8; jt++) acc1[jt] = (f32x4){0.f, 0.f, 0.f, 0.f};

    for (int kh = 0; kh < 2; kh++) {
        __syncthreads(); // kh=1: bufB reads of kh=0 done
        {
            const unsigned int* src = (const unsigned int*)kpb;
            for (int i = tid; i < 128 * 32; i += 256) {
                int j = i >> 5, mu = i & 31;
                ((unsigned int*)&bufB[j * 72])[mu] =
                    src[(chunkbase + j) * 64 + kh * 32 + mu];
            }
        }
        __syncthreads();
#pragma unroll
        for (int kt2 = 0; kt2 < 2; kt2++) {
            short8 a = *(const short8*)&bufA[(16 * wv + fr) * 136 + kh * 64 +
                                             kt2 * 32 + fq * 8];
            for (int jt = 0; jt < jtmax; jt++) {
                short8 bb =
                    *(const short8*)&bufB[(16 * jt + fr) * 72 + kt2 * 32 + fq * 8];
                acc1[jt] =
                    __builtin_amdgcn_mfma_f32_16x16x32_bf16(a, bb, acc1[jt], 0, 0, 0);
            }
        }
    }
    // mask (tril incl diag) + C/D->A-operand relayout through LDS (bf16)
#pragma unroll
    for (int jt = 0; jt < 8; jt++) {
#pragma unroll
        for (int reg = 0; reg < 4; reg++) {
            const int nloc = 16 * wv + fq * 4 + reg;
            const int j = 16 * jt + fr;
            float val = (jt < jtmax && j <= half * 64 + nloc) ? acc1[jt][reg] : 0.f;
            bufC[nloc * 136 + j] = (short)f2bf(val);
        }
    }
    __syncthreads(); // Pb visible; bufB free

    // stage S0^T: Gp slot fp32 [m 128][e 64] -> bufB bf16 [e][136]
    const int s0base = (h * 32 + c * 4) * (M * D);
    for (int i = tid; i < 128 * 16; i += 256) {
        int m = i >> 4, e4 = (i & 15) * 4;
        float4 g = *(const float4*)&Gp[s0base + m * 64 + e4];
        bufB[(e4 + 0) * 136 + m] = (short)f2bf(g.x);
        bufB[(e4 + 1) * 136 + m] = (short)f2bf(g.y);
        bufB[(e4 + 2) * 136 + m] = (short)f2bf(g.z);
        bufB[(e4 + 3) * 136 + m] = (short)f2bf(g.w);
    }
    __syncthreads();

    f32x4 acc2[4];
#pragma unroll
    for (int et = 0; et < 4; et++) acc2[et] = (f32x4){0.f, 0.f, 0.f, 0.f};
    // out += W @ S0  (A = Wb, B = S0T)
#pragma unroll
    for (int kt = 0; kt < 4; kt++) {
        short8 a = *(const short8*)&bufA[(16 * wv + fr) * 136 + kt * 32 + fq * 8];
#pragma unroll
        for (int et = 0; et < 4; et++) {
            short8 bb = *(const short8*)&bufB[(16 * et + fr) * 136 + kt * 32 + fq * 8];
            acc2[et] = __builtin_amdgcn_mfma_f32_16x16x32_bf16(a, bb, acc2[et], 0, 0, 0);
        }
    }
    __syncthreads(); // S0T reads done

    // stage V^T: v fp32 [j 128][e 64] -> bufB bf16 [e][136]
    for (int i = tid; i < 128 * 16; i += 256) {
        int j = i >> 4, e4 = (i & 15) * 4;
        float4 g = *(const float4*)&v[(chunkbase + j) * 64 + e4];
        bufB[(e4 + 0) * 136 + j] = (short)f2bf(g.x);
        bufB[(e4 + 1) * 136 + j] = (short)f2bf(g.y);
        bufB[(e4 + 2) * 136 + j] = (short)f2bf(g.z);
        bufB[(e4 + 3) * 136 + j] = (short)f2bf(g.w);
    }
    __syncthreads();

    // out += P @ V  (A = Pb, B = VT). half 0: Pb cols j>=64 are zero -> K=64.
    const int ktmax = half ? 4 : 2;
    for (int kt = 0; kt < ktmax; kt++) {
        short8 a = *(const short8*)&bufC[(16 * wv + fr) * 136 + kt * 32 + fq * 8];
#pragma unroll
        for (int et = 0; et < 4; et++) {
            short8 bb = *(const short8*)&bufB[(16 * et + fr) * 136 + kt * 32 + fq * 8];
            acc2[et] = __builtin_amdgcn_mfma_f32_16x16x32_bf16(a, bb, acc2[et], 0, 0, 0);
        }
    }

    // epilogue: C/D layout -> global fp32
#pragma unroll
    for (int et = 0; et < 4; et++) {
#pragma unroll
        for (int reg = 0; reg < 4; reg++) {
            out[(rowbase + 16 * wv + fq * 4 + reg) * D + 16 * et + fr] =
                acc2[et][reg];
        }
    }
}

extern "C" void kernel_launch(void* const* d_in, const int* in_sizes, int n_in,
                              void* d_out, int out_size, void* d_ws, size_t ws_size,
                              hipStream_t stream) {
    const float* q = (const float*)d_in[0];
    const float* k = (const float*)d_in[1];
    const float* v = (const float*)d_in[2];
    const float* proj = (const float*)d_in[3];
    float* out = (float*)d_out;

    // workspace (float slots): qp 1M, kp 1M, kpart 32K, Gp 2M,
    // kpb 512K (bf16 x 1M), WbG 512K (bf16 x 1M)  => ~21 MB total
    float* ws = (float*)d_ws;
    float* qp = ws;
    float* kp = qp + H * N * M;
    float* kpart = kp + H * N * M;
    float* Gp = kpart + H * 32 * M;
    unsigned short* kpb = (unsigned short*)(Gp + H * 32 * M * D);
    unsigned short* WbG = kpb + H * N * M;

    k_projg<<<dim3(32, H, 2), 256, 0, stream>>>(q, k, proj, v, qp, kp, kpb, Gp,
                                                kpart);
    k_fix<<<384, 256, 0, stream>>>(qp, kp, kpart, Gp, WbG);
    k_attn<<<dim3(H * NC, 2), 256, 0, stream>>>(WbG, kpb, Gp, v, out);
}